// Round 14
// baseline (9820.696 us; speedup 1.0000x reference)
//
#include <hip/hip_runtime.h>
#include <hip/hip_fp16.h>

typedef unsigned int u32;
typedef unsigned short u16;
typedef unsigned long long u64;

#define DEV static __device__ __forceinline__

DEV float sigf(float x){ return 1.0f / (1.0f + expf(-x)); }

DEV u64  ldA64(const u64* p){ return __hip_atomic_load(p, __ATOMIC_RELAXED, __HIP_MEMORY_SCOPE_AGENT); }
DEV void stA64(u64* p, u64 v){ __hip_atomic_store(p, v, __ATOMIC_RELAXED, __HIP_MEMORY_SCOPE_AGENT); }
DEV float ldAf(const float* p){ return __hip_atomic_load(p, __ATOMIC_RELAXED, __HIP_MEMORY_SCOPE_AGENT); }
DEV void stAf(float* p, float v){ __hip_atomic_store(p, v, __ATOMIC_RELAXED, __HIP_MEMORY_SCOPE_AGENT); }
DEV u32  ldA32(const u32* p){ return __hip_atomic_load(p, __ATOMIC_RELAXED, __HIP_MEMORY_SCOPE_AGENT); }

// tagged h exchange: hi32 = f32 bits, lo32 = step tag
DEV u64 packHV(float h, u32 tag){ return (((u64)__float_as_uint(h)) << 32) | (u64)tag; }
DEV float unpackH(u64 v){ return __uint_as_float((u32)(v >> 32)); }

// tagged argmax key: [mapped f32 (32b)][0x1FFFF - row (17b)][tag (15b)]
DEV u64 packKeyT(float v, u32 row, u32 tagv){
  u32 u = __float_as_uint(v);
  u = (u & 0x80000000u) ? ~u : (u | 0x80000000u);
  return (((u64)u) << 32) | ((u64)(0x1FFFFu - row) << 15) | (u64)tagv;
}

// fp16 row fragment (8 halves in a uint4) dotted with 8 f32 inputs (f32 math)
DEV float dot8h(const uint4 A, const float4 a, const float4 b){
  const __half2* h = (const __half2*)&A;
  const float2 f0 = __half22float2(h[0]);
  const float2 f1 = __half22float2(h[1]);
  const float2 f2 = __half22float2(h[2]);
  const float2 f3 = __half22float2(h[3]);
  float s;
  s  = f0.x*a.x + f0.y*a.y + f1.x*a.z + f1.y*a.w;
  s += f2.x*b.x + f2.y*b.y + f3.x*b.z + f3.y*b.w;
  return s;
}

DEV float dotrow(const float4 A, const float4 B, const float4 Cc, const float4 D,
                 const float4 q0, const float4 q1, const float4 q2, const float4 q3){
  float s;
  s  = A.x*q0.x + A.y*q0.y + A.z*q0.z + A.w*q0.w;
  s += B.x*q1.x + B.y*q1.y + B.z*q1.z + B.w*q1.w;
  s += Cc.x*q2.x + Cc.y*q2.y + Cc.z*q2.z + Cc.w*q2.w;
  s += D.x*q3.x + D.y*q3.y + D.z*q3.z + D.w*q3.w;
  return s;
}

// ---------------- LDS ----------------
struct SM {
  float w1s[24576];    // 96 KB decoder layer-1 weights (thread-SoA)
  float inpP[1600];
  float linp[1024];    // h1(t) raw; doubles as h1 cache for L1(t+1)
  float h0c[1024];     // h0(t) raw cache (filled during L1's poll) for L0(t+1)
  float srow[200];
  float erow[200];
  float red[8];
  float dots[16];
  float cst0[4];
  float cst1[4];
  u64   wkey[4];
};

template<int CPT> DEV int pidx(int c){ int b = c / CPT; return b * (CPT + 4) + (c - b * CPT); }

template<int CPT, int DIN>
DEV void loadw(float* wreg, const float* Wih, const float* Whh, int jb4){
  const int tid = threadIdx.x, r = tid >> 4, p = tid & 15;
  const int R = 512 * (r >> 2) + jb4 + (r & 3);
  const float* s1 = Wih + (size_t)R * DIN;
  const float* s2 = Whh + (size_t)R * 512;
  #pragma unroll
  for (int k = 0; k < CPT; k += 4){
    const int col = p * CPT + k;
    const float4 v = *(const float4*)((col < DIN) ? (s1 + col) : (s2 + col - DIN));
    wreg[k] = v.x; wreg[k+1] = v.y; wreg[k+2] = v.z; wreg[k+3] = v.w;
  }
}

template<int CPT>
DEV void dot16(const float* wreg, const float* inpP, float* dots){
  const int tid = threadIdx.x, p = tid & 15;
  const float* xi = inpP + p * (CPT + 4);
  float acc = 0.f;
  #pragma unroll
  for (int k = 0; k < CPT; k += 4){
    const float4 xv = *(const float4*)(xi + k);
    acc = fmaf(wreg[k],   xv.x, acc);
    acc = fmaf(wreg[k+1], xv.y, acc);
    acc = fmaf(wreg[k+2], xv.z, acc);
    acc = fmaf(wreg[k+3], xv.w, acc);
  }
  #pragma unroll
  for (int s = 1; s < 16; s <<= 1) acc += __shfl_xor(acc, s, 64);
  if (p == 0) dots[tid >> 4] = acc;
}

DEV void dot16_w1(const float* w1s, const float* inpP, float* dots){
  const int tid = threadIdx.x, p = tid & 15;
  const float* xi = inpP + p * 100;
  float acc = 0.f;
  #pragma unroll
  for (int k = 0; k < 96; k += 4){
    const float4 w4 = *(const float4*)(w1s + (k >> 2) * 1024 + tid * 4);
    const float4 xv = *(const float4*)(xi + k);
    acc = fmaf(w4.x, xv.x, acc);
    acc = fmaf(w4.y, xv.y, acc);
    acc = fmaf(w4.z, xv.z, acc);
    acc = fmaf(w4.w, xv.w, acc);
  }
  #pragma unroll
  for (int s = 1; s < 16; s <<= 1) acc += __shfl_xor(acc, s, 64);
  if (p == 0) dots[tid >> 4] = acc;
}

// ---------------- phase barrier (used twice, encoder only) ----------------
DEV void gbar_phase(u32* g, u32 ev){
  __syncthreads();
  if (threadIdx.x == 0){
    __hip_atomic_fetch_add(g, 1u, __ATOMIC_RELEASE, __HIP_MEMORY_SCOPE_AGENT);
    const u32 tgt = 256u * ev;
    while (ldA32(g) < tgt) __builtin_amdgcn_s_sleep(8);
    (void)__hip_atomic_fetch_add(g, 0u, __ATOMIC_ACQUIRE, __HIP_MEMORY_SCOPE_AGENT);
    asm volatile("" ::: "memory");
  }
  __syncthreads();
}

// ---------------- encoder layer (R7/R11 verbatim) ----------------
template<int DIN, bool WRITE_XS>
DEV void enc_layer(const float* __restrict__ xg, float* __restrict__ xs_out,
                   const float* __restrict__ Wih, const float* __restrict__ Whh,
                   const float* __restrict__ bias,
                   u64* __restrict__ ht, float* __restrict__ hfinL, float* __restrict__ cfinL,
                   const int dir, const int jb4, SM& sm)
{
  constexpr int CPT = (DIN + 512) / 16;
  constexpr int NX  = DIN / 256;
  const int tid = threadIdx.x;
  float wreg[CPT];
  loadw<CPT, DIN>(wreg, Wih + (size_t)dir * 2048 * DIN, Whh + (size_t)dir * 2048 * 512, jb4);
  float b_i = 0.f, b_f = 0.f, b_g = 0.f, b_o = 0.f;
  if (tid < 4){
    const int j = jb4 + tid;
    sm.cst0[tid] = 0.f;
    b_i = bias[dir*2048 +        j];
    b_f = bias[dir*2048 +  512 + j];
    b_g = bias[dir*2048 + 1024 + j];
    b_o = bias[dir*2048 + 1536 + j];
  }
  float xr[NX];
  {
    const int t0 = dir ? 1023 : 0;
    #pragma unroll
    for (int i = 0; i < NX; ++i){
      const int c = tid + 256 * i;
      xr[i] = (DIN == 512) ? xg[(size_t)t0 * DIN + c] : ldAf(xg + (size_t)t0 * DIN + c);
    }
  }
  for (int step = 0; step < 1024; ++step){
    #pragma unroll
    for (int i = 0; i < NX; ++i) sm.inpP[pidx<CPT>(tid + 256 * i)] = xr[i];
    {
      const u64* hp = ht + (step & 1) * 512;
      const u32 want = (u32)step;
      u64 a = ldA64(hp + tid*2), b = ldA64(hp + tid*2 + 1);
      while ((u32)a != want){ __builtin_amdgcn_s_sleep(1); a = ldA64(hp + tid*2); }
      while ((u32)b != want){ __builtin_amdgcn_s_sleep(1); b = ldA64(hp + tid*2 + 1); }
      sm.inpP[pidx<CPT>(DIN + tid*2)]     = unpackH(a);
      sm.inpP[pidx<CPT>(DIN + tid*2 + 1)] = unpackH(b);
    }
    __syncthreads();
    if (step < 1023){
      const int tn = dir ? (1022 - step) : (step + 1);
      #pragma unroll
      for (int i = 0; i < NX; ++i){
        const int c = tid + 256 * i;
        xr[i] = (DIN == 512) ? xg[(size_t)tn * DIN + c] : ldAf(xg + (size_t)tn * DIN + c);
      }
    }
    dot16<CPT>(wreg, sm.inpP, sm.dots);
    __syncthreads();
    if (tid < 4){
      const float gi = sm.dots[tid]      + b_i;
      const float gf = sm.dots[4 + tid]  + b_f;
      const float gg = sm.dots[8 + tid]  + b_g;
      const float go = sm.dots[12 + tid] + b_o;
      const float cc = sigf(gf) * sm.cst0[tid] + sigf(gi) * tanhf(gg);
      const float hh = sigf(go) * tanhf(cc);
      sm.cst0[tid] = cc;
      const int t = dir ? (1023 - step) : step;
      const int j = jb4 + tid;
      stA64(ht + ((step + 1) & 1) * 512 + j, packHV(hh, (u32)(step + 1)));
      if (WRITE_XS) stAf(xs_out + (size_t)t * 1024 + dir * 512 + j, hh);
      if (step == 1023){ stAf(hfinL + dir*512 + j, hh); stAf(cfinL + dir*512 + j, cc); }
    }
    __syncthreads();
  }
}

// ---------------- init ----------------
__global__ void bilstm_init(u32* ws){
  for (u32 i = threadIdx.x; i < 32768u; i += 256u) ws[i] = 0u;
}

// ---------------- lin_W f32 -> fp16 + per-row max|w| (R11 verbatim) ----------------
__global__ void cvt_lin(const float* __restrict__ w, uint4* __restrict__ o,
                        float* __restrict__ maxw, const int C){
  const int wv = threadIdx.x >> 6, lane = threadIdx.x & 63;
  const int stride = gridDim.x * 4;
  for (int r = blockIdx.x * 4 + wv; r < C; r += stride){
    const float4* src = (const float4*)(w + (size_t)r * 1024) + lane * 4;
    const float4 v0 = src[0], v1 = src[1], v2 = src[2], v3 = src[3];
    uint4 p0, p1;
    __half2 h;
    h = __floats2half2_rn(v0.x, v0.y); p0.x = *(const u32*)&h;
    h = __floats2half2_rn(v0.z, v0.w); p0.y = *(const u32*)&h;
    h = __floats2half2_rn(v1.x, v1.y); p0.z = *(const u32*)&h;
    h = __floats2half2_rn(v1.z, v1.w); p0.w = *(const u32*)&h;
    h = __floats2half2_rn(v2.x, v2.y); p1.x = *(const u32*)&h;
    h = __floats2half2_rn(v2.z, v2.w); p1.y = *(const u32*)&h;
    h = __floats2half2_rn(v3.x, v3.y); p1.z = *(const u32*)&h;
    h = __floats2half2_rn(v3.z, v3.w); p1.w = *(const u32*)&h;
    uint4* dst = o + (size_t)r * 128 + lane * 2;
    dst[0] = p0; dst[1] = p1;
    float m = fmaxf(fmaxf(fmaxf(fabsf(v0.x), fabsf(v0.y)), fmaxf(fabsf(v0.z), fabsf(v0.w))),
                    fmaxf(fmaxf(fabsf(v1.x), fabsf(v1.y)), fmaxf(fabsf(v1.z), fabsf(v1.w))));
    m = fmaxf(m, fmaxf(fmaxf(fabsf(v2.x), fabsf(v2.y)), fmaxf(fabsf(v2.z), fabsf(v2.w))));
    m = fmaxf(m, fmaxf(fmaxf(fabsf(v3.x), fabsf(v3.y)), fmaxf(fabsf(v3.z), fabsf(v3.w))));
    #pragma unroll
    for (int s = 1; s < 64; s <<= 1) m = fmaxf(m, __shfl_xor(m, s, 64));
    if (lane == 0) maxw[r] = m;
  }
}

// ---------------- persistent kernel ----------------
template<int LINFP16>
__global__ __launch_bounds__(256, 1)
void bilstm_persist(const float* __restrict__ x,
                    const float* __restrict__ eW0, const float* __restrict__ eU0, const float* __restrict__ eb0,
                    const float* __restrict__ eW1, const float* __restrict__ eU1, const float* __restrict__ eb1,
                    const float* __restrict__ dW0, const float* __restrict__ dU0, const float* __restrict__ db0,
                    const float* __restrict__ dW1, const float* __restrict__ dU1, const float* __restrict__ db1,
                    const float* __restrict__ linW, const float* __restrict__ linb,
                    const float* __restrict__ emb, const float* __restrict__ bos,
                    float* __restrict__ out, float* __restrict__ ws, const int L, const int C)
{
  __shared__ SM sm;
  const int w = blockIdx.x;
  const int tid = threadIdx.x;
  const int dir = (w >> 2) & 1;                    // dir confined to 4 XCDs
  const int jb4 = ((w >> 3) * 4 + (w & 3)) * 4;

  u64*  htagE = (u64*)ws;                          // [0,32768)
  u64*  h0t   = htagE + 4096;                      // [32768,49152)
  u64*  h1t   = h0t + 2048;                        // [49152,65536)
  float* hfin = (float*)(h1t + 2048);              // [65536,73728)
  float* cfin = hfin + 2048;                       // [73728,81920)
  u32*  gbar  = (u32*)(cfin + 2048);               // [81920,81924)
  u64*  gkey  = (u64*)((char*)ws + 98304);         // [98304,131072): 256 x 128B slots
  const u16*  linH = (const u16*)((const char*)ws + 131072);
  const float* maxw = (const float*)((const char*)ws + 131072 + (size_t)C * 2048);
  float* xs1  = out;                               // scratch; decoder rewrites all of out

  // ================= encoder =================
  enc_layer<512,  true >(x,   xs1,     eW0, eU0, eb0, htagE + (0*2 + dir)*1024, hfin,        cfin,        dir, jb4, sm);
  gbar_phase(gbar, 1);
  enc_layer<1024, false>(xs1, nullptr, eW1, eU1, eb1, htagE + (1*2 + dir)*1024, hfin + 1024, cfin + 1024, dir, jb4, sm);
  gbar_phase(gbar, 2);

  // ================= decoder =================
  float w0reg[64];
  loadw<64, 512>(w0reg, dW0 + (size_t)dir*2048*512, dU0 + (size_t)dir*2048*512, jb4);
  { // stage layer-1 weights into LDS SoA
    const int r = tid >> 4, p = tid & 15;
    const int R = 512 * (r >> 2) + jb4 + (r & 3);
    const float* s1 = dW1 + (size_t)dir*2048*1024 + (size_t)R * 1024;
    const float* s2 = dU1 + (size_t)dir*2048*512  + (size_t)R * 512;
    #pragma unroll
    for (int k = 0; k < 96; k += 4){
      const int col = p * 96 + k;
      const float4 v = *(const float4*)((col < 1024) ? (s1 + col) : (s2 + col - 1024));
      *(float4*)(sm.w1s + (k >> 2) * 1024 + tid * 4) = v;
    }
  }

  float b0i=0,b0f=0,b0g=0,b0o=0, b1i=0,b1f=0,b1g=0,b1o=0;
  if (tid < 4){
    const int j = jb4 + tid;
    sm.cst0[tid] = ldAf(&cfin[dir*512 + j]);
    sm.cst1[tid] = ldAf(&cfin[1024 + dir*512 + j]);
    b0i = db0[dir*2048 + j];        b0f = db0[dir*2048 + 512 + j];
    b0g = db0[dir*2048 + 1024 + j]; b0o = db0[dir*2048 + 1536 + j];
    b1i = db1[dir*2048 + j];        b1f = db1[dir*2048 + 512 + j];
    b1g = db1[dir*2048 + 1024 + j]; b1o = db1[dir*2048 + 1536 + j];
  }
  const int rbase = w * 196 + (w < 81 ? w : 81);
  const int rn    = 196 + (w < 81 ? 1 : 0);
  int tok = 0;

  for (int t = 0; t < L; ++t){
    const u32 tag = (u32)(t + 1);
    // ---- layer 0 (h-half from h0c LDS cache for t>0) ----
    {
      const float* src = (t == 0) ? bos : (emb + (size_t)tok * 512);
      sm.inpP[pidx<64>(tid)]       = src[tid];
      sm.inpP[pidx<64>(tid + 256)] = src[tid + 256];
      if (t == 0){
        sm.inpP[pidx<64>(512 + tid*2)]     = ldAf(&hfin[dir*512 + tid*2]);
        sm.inpP[pidx<64>(512 + tid*2 + 1)] = ldAf(&hfin[dir*512 + tid*2 + 1]);
      } else {
        sm.inpP[pidx<64>(512 + tid*2)]     = sm.h0c[dir*512 + tid*2];
        sm.inpP[pidx<64>(512 + tid*2 + 1)] = sm.h0c[dir*512 + tid*2 + 1];
      }
      __syncthreads();
      dot16<64>(w0reg, sm.inpP, sm.dots);
      __syncthreads();
      if (tid < 4){
        const float gi = sm.dots[tid] + b0i, gf = sm.dots[4+tid] + b0f;
        const float gg = sm.dots[8+tid] + b0g, go = sm.dots[12+tid] + b0o;
        const float cc = sigf(gf) * sm.cst0[tid] + sigf(gi) * tanhf(gg);
        const float hh = sigf(go) * tanhf(cc);
        sm.cst0[tid] = cc;
        stA64(h0t + (dir*2 + (t & 1))*512 + jb4 + tid, packHV(hh, tag));
      }
      __syncthreads();
    }

    // ---- layer 1 (polls h0(t); h1(t-1) from linp cache) ----
    {
      #pragma unroll
      for (int i = 0; i < 4; ++i){
        const int c = tid + 256 * i;
        const int d = c >> 9, idx = c & 511;
        const u64* hp = h0t + (d*2 + (t & 1)) * 512 + idx;
        u64 v = ldA64(hp);
        while ((u32)v != tag){ __builtin_amdgcn_s_sleep(1); v = ldA64(hp); }
        const float hv = unpackH(v);
        sm.inpP[pidx<96>(c)] = hv;
        sm.h0c[c] = hv;                              // cache for L0(t+1)
      }
      if (t == 0){
        sm.inpP[pidx<96>(1024 + tid*2)]     = ldAf(&hfin[1024 + dir*512 + tid*2]);
        sm.inpP[pidx<96>(1024 + tid*2 + 1)] = ldAf(&hfin[1024 + dir*512 + tid*2 + 1]);
      } else {
        sm.inpP[pidx<96>(1024 + tid*2)]     = sm.linp[dir*512 + tid*2];
        sm.inpP[pidx<96>(1024 + tid*2 + 1)] = sm.linp[dir*512 + tid*2 + 1];
      }
      __syncthreads();
      dot16_w1(sm.w1s, sm.inpP, sm.dots);
      __syncthreads();
      if (tid < 4){
        const float gi = sm.dots[tid] + b1i, gf = sm.dots[4+tid] + b1f;
        const float gg = sm.dots[8+tid] + b1g, go = sm.dots[12+tid] + b1o;
        const float cc = sigf(gf) * sm.cst1[tid] + sigf(gi) * tanhf(gg);
        const float hh = sigf(go) * tanhf(cc);
        sm.cst1[tid] = cc;
        stA64(h1t + (dir*2 + (t & 1))*512 + jb4 + tid, packHV(hh, tag));
      }
    }

    // ---- linear + local argmax (scan loads software-pipelined) ----
    {
      float pabs = 0.f;
      #pragma unroll
      for (int i = 0; i < 4; ++i){
        const int c = tid + 256 * i;
        const int d = c >> 9, idx = c & 511;
        const u64* hp = h1t + (d*2 + (t & 1)) * 512 + idx;
        u64 v = ldA64(hp);
        while ((u32)v != tag){ __builtin_amdgcn_s_sleep(1); v = ldA64(hp); }
        const float hv = unpackH(v);
        sm.linp[c] = hv;                             // doubles as h1 cache for L1(t+1)
        pabs += fabsf(hv);
      }
      const int wv = tid >> 6, lane = tid & 63;
      if constexpr (LINFP16){
        #pragma unroll
        for (int s = 1; s < 64; s <<= 1) pabs += __shfl_xor(pabs, s, 64);
        if (lane == 0) sm.red[wv] = pabs;
      }
      __syncthreads();

      const float4* ip4 = (const float4*)(sm.linp + lane * 16);
      const float4 q0 = ip4[0], q1 = ip4[1], q2 = ip4[2], q3 = ip4[3];
      u64 kmax = 0;
      const int rmaxr = rbase + rn - 1;

      if constexpr (LINFP16){
        const float sumabs = sm.red[0] + sm.red[1] + sm.red[2] + sm.red[3];
        const float cErr = sumabs * 7.5e-4f;
        float lb = -1e30f;

        int idc[4];
        uint4 c0[4], c1[4];
        { // prologue: load first batch
          const int i0 = wv;
          #pragma unroll
          for (int j = 0; j < 4; ++j){
            int i = i0 + 4 * j; if (i > rn - 1) i = rn - 1;
            idc[j] = i;
            const uint4* p = (const uint4*)(linH + (size_t)(rbase + i) * 1024) + lane * 2;
            c0[j] = p[0]; c1[j] = p[1];
          }
        }
        for (int i0 = wv; i0 < rn; i0 += 16){
          const int i1 = i0 + 16;
          int idn[4];
          uint4 n0[4], n1[4];
          if (i1 < rn){ // issue next batch's loads before reducing current
            #pragma unroll
            for (int j = 0; j < 4; ++j){
              int i = i1 + 4 * j; if (i > rn - 1) i = rn - 1;
              idn[j] = i;
              const uint4* p = (const uint4*)(linH + (size_t)(rbase + i) * 1024) + lane * 2;
              n0[j] = p[0]; n1[j] = p[1];
            }
          }
          float s0 = dot8h(c0[0], q0, q1) + dot8h(c1[0], q2, q3);
          float s1 = dot8h(c0[1], q0, q1) + dot8h(c1[1], q2, q3);
          float s2 = dot8h(c0[2], q0, q1) + dot8h(c1[2], q2, q3);
          float s3 = dot8h(c0[3], q0, q1) + dot8h(c1[3], q2, q3);
          #pragma unroll
          for (int sh = 1; sh < 64; sh <<= 1){
            s0 += __shfl_xor(s0, sh, 64);
            s1 += __shfl_xor(s1, sh, 64);
            s2 += __shfl_xor(s2, sh, 64);
            s3 += __shfl_xor(s3, sh, 64);
          }
          if (lane == 0){
            const int ra = rbase + idc[0], rb = rbase + idc[1];
            const int rc = rbase + idc[2], rd = rbase + idc[3];
            const float sa = s0 + linb[ra], sb = s1 + linb[rb];
            const float sc = s2 + linb[rc], sd = s3 + linb[rd];
            out[(size_t)t * C + ra] = sa;
            out[(size_t)t * C + rb] = sb;
            out[(size_t)t * C + rc] = sc;
            out[(size_t)t * C + rd] = sd;
            const float ea = maxw[ra] * cErr + 1e-4f;
            const float eb = maxw[rb] * cErr + 1e-4f;
            const float ec = maxw[rc] * cErr + 1e-4f;
            const float ed = maxw[rd] * cErr + 1e-4f;
            sm.srow[idc[0]] = sa; sm.erow[idc[0]] = ea;
            sm.srow[idc[1]] = sb; sm.erow[idc[1]] = eb;
            sm.srow[idc[2]] = sc; sm.erow[idc[2]] = ec;
            sm.srow[idc[3]] = sd; sm.erow[idc[3]] = ed;
            lb = fmaxf(lb, sa - ea); lb = fmaxf(lb, sb - eb);
            lb = fmaxf(lb, sc - ec); lb = fmaxf(lb, sd - ed);
          }
          if (i1 < rn){
            #pragma unroll
            for (int j = 0; j < 4; ++j){ idc[j] = idn[j]; c0[j] = n0[j]; c1[j] = n1[j]; }
          }
        }
        if (lane == 0) sm.red[4 + wv] = lb;
        __syncthreads();
        const float Lb = fmaxf(fmaxf(sm.red[4], sm.red[5]), fmaxf(sm.red[6], sm.red[7]));
        // exact f32 recheck of candidates (provably includes the WG's true argmax)
        for (int i = wv; i < rn; i += 4){
          if (sm.srow[i] + sm.erow[i] >= Lb){
            const int row = rbase + i;
            const float4* wp = (const float4*)(linW + (size_t)row * 1024) + lane * 4;
            float s = dotrow(wp[0], wp[1], wp[2], wp[3], q0, q1, q2, q3);
            #pragma unroll
            for (int sh2 = 1; sh2 < 64; sh2 <<= 1) s += __shfl_xor(s, sh2, 64);
            if (lane == 0){
              s += linb[row];
              const u64 k = packKeyT(s, (u32)row, tag);
              if (k > kmax) kmax = k;
            }
          }
        }
      } else {
        for (int i0 = wv; i0 < rn; i0 += 16){
          const int ra = rbase + i0;
          const int rb = (ra + 4  > rmaxr) ? rmaxr : ra + 4;
          const int rc = (ra + 8  > rmaxr) ? rmaxr : ra + 8;
          const int rd = (ra + 12 > rmaxr) ? rmaxr : ra + 12;
          const float ba = linb[ra], bb = linb[rb], bc = linb[rc], bd = linb[rd];
          const float4* pa = (const float4*)(linW + (size_t)ra * 1024) + lane * 4;
          const float4* pb = (const float4*)(linW + (size_t)rb * 1024) + lane * 4;
          const float4* pc = (const float4*)(linW + (size_t)rc * 1024) + lane * 4;
          const float4* pd = (const float4*)(linW + (size_t)rd * 1024) + lane * 4;
          const float4 a0 = pa[0], a1 = pa[1], a2 = pa[2], a3 = pa[3];
          const float4 e0 = pb[0], e1 = pb[1], e2 = pb[2], e3 = pb[3];
          const float4 c0 = pc[0], c1 = pc[1], c2 = pc[2], c3 = pc[3];
          const float4 d0 = pd[0], d1 = pd[1], d2 = pd[2], d3 = pd[3];
          float sa = dotrow(a0,a1,a2,a3, q0,q1,q2,q3);
          float sb = dotrow(e0,e1,e2,e3, q0,q1,q2,q3);
          float sc = dotrow(c0,c1,c2,c3, q0,q1,q2,q3);
          float sd = dotrow(d0,d1,d2,d3, q0,q1,q2,q3);
          #pragma unroll
          for (int sh = 1; sh < 64; sh <<= 1){
            sa += __shfl_xor(sa, sh, 64);
            sb += __shfl_xor(sb, sh, 64);
            sc += __shfl_xor(sc, sh, 64);
            sd += __shfl_xor(sd, sh, 64);
          }
          if (lane == 0){
            sa += ba; sb += bb; sc += bc; sd += bd;
            out[(size_t)t * C + ra] = sa;
            out[(size_t)t * C + rb] = sb;
            out[(size_t)t * C + rc] = sc;
            out[(size_t)t * C + rd] = sd;
            u64 k;
            k = packKeyT(sa, (u32)ra, tag); if (k > kmax) kmax = k;
            k = packKeyT(sb, (u32)rb, tag); if (k > kmax) kmax = k;
            k = packKeyT(sc, (u32)rc, tag); if (k > kmax) kmax = k;
            k = packKeyT(sd, (u32)rd, tag); if (k > kmax) kmax = k;
          }
        }
      }
      if (lane == 0) sm.wkey[wv] = kmax;
    }

    // ---- distributed argmax exchange (R7/R11 verbatim) ----
    __syncthreads();
    if (tid == 0){
      u64 k4 = sm.wkey[0];
      if (sm.wkey[1] > k4) k4 = sm.wkey[1];
      if (sm.wkey[2] > k4) k4 = sm.wkey[2];
      if (sm.wkey[3] > k4) k4 = sm.wkey[3];
      stA64(gkey + (size_t)w * 16, k4);              // own 128-B slot: no contention
    }
    __syncthreads();
    {
      const u64* p = gkey + (size_t)tid * 16;        // thread i polls WG i's slot
      u64 kv = ldA64(p);
      while ((u32)(kv & 0x7FFFu) != tag){ __builtin_amdgcn_s_sleep(1); kv = ldA64(p); }
      #pragma unroll
      for (int s = 1; s < 64; s <<= 1){
        const u64 o = (u64)__shfl_xor((unsigned long long)kv, s, 64);
        if (o > kv) kv = o;
      }
      if ((tid & 63) == 0) sm.wkey[tid >> 6] = kv;
    }
    __syncthreads();
    {
      u64 gk = sm.wkey[0];
      if (sm.wkey[1] > gk) gk = sm.wkey[1];
      if (sm.wkey[2] > gk) gk = sm.wkey[2];
      if (sm.wkey[3] > gk) gk = sm.wkey[3];
      tok = (int)(0x1FFFFu - ((u32)(gk >> 15) & 0x1FFFFu));
      if (w == 0 && tid == 0) out[(size_t)L * C + t] = (float)tok;
    }
  }
}

// ---------------- launch ----------------
extern "C" void kernel_launch(void* const* d_in, const int* in_sizes, int n_in,
                              void* d_out, int out_size, void* d_ws, size_t ws_size,
                              hipStream_t stream)
{
  const float* x    = (const float*)d_in[0];
  const float* eW0  = (const float*)d_in[1];
  const float* eU0  = (const float*)d_in[2];
  const float* eb0  = (const float*)d_in[3];
  const float* eW1  = (const float*)d_in[4];
  const float* eU1  = (const float*)d_in[5];
  const float* eb1  = (const float*)d_in[6];
  const float* dW0  = (const float*)d_in[7];
  const float* dU0  = (const float*)d_in[8];
  const float* db0  = (const float*)d_in[9];
  const float* dW1  = (const float*)d_in[10];
  const float* dU1  = (const float*)d_in[11];
  const float* db1  = (const float*)d_in[12];
  const float* linW = (const float*)d_in[13];
  const float* linb = (const float*)d_in[14];
  const float* emb  = (const float*)d_in[15];
  const float* bos  = (const float*)d_in[16];

  const int C = in_sizes[14];            // 50257
  const int L = out_size / (C + 1);      // 150
  const int nlin = in_sizes[13];         // C*1024

  const size_t need = 131072 + (size_t)nlin * 2 + (size_t)C * 4;
  const bool fp16lin = (ws_size >= need);

  hipLaunchKernelGGL(bilstm_init, dim3(1), dim3(256), 0, stream, (u32*)d_ws);
  if (fp16lin){
    hipLaunchKernelGGL(cvt_lin, dim3(2048), dim3(256), 0, stream,
                       linW, (uint4*)((char*)d_ws + 131072),
                       (float*)((char*)d_ws + 131072 + (size_t)C * 2048), C);
    hipLaunchKernelGGL((bilstm_persist<1>), dim3(256), dim3(256), 0, stream,
                       x, eW0, eU0, eb0, eW1, eU1, eb1,
                       dW0, dU0, db0, dW1, dU1, db1,
                       linW, linb, emb, bos,
                       (float*)d_out, (float*)d_ws, L, C);
  } else {
    hipLaunchKernelGGL((bilstm_persist<0>), dim3(256), dim3(256), 0, stream,
                       x, eW0, eU0, eb0, eW1, eU1, eb1,
                       dW0, dU0, db0, dW1, dU1, db1,
                       linW, linb, emb, bos,
                       (float*)d_out, (float*)d_ws, L, C);
  }
}

// Round 15
// 8317.188 us; speedup vs baseline: 1.1808x; 1.1808x over previous
//
#include <hip/hip_runtime.h>
#include <hip/hip_fp16.h>

typedef unsigned int u32;
typedef unsigned short u16;
typedef unsigned long long u64;

#define DEV static __device__ __forceinline__

DEV float sigf(float x){ return 1.0f / (1.0f + expf(-x)); }

DEV u64  ldA64(const u64* p){ return __hip_atomic_load(p, __ATOMIC_RELAXED, __HIP_MEMORY_SCOPE_AGENT); }
DEV void stA64(u64* p, u64 v){ __hip_atomic_store(p, v, __ATOMIC_RELAXED, __HIP_MEMORY_SCOPE_AGENT); }
DEV float ldAf(const float* p){ return __hip_atomic_load(p, __ATOMIC_RELAXED, __HIP_MEMORY_SCOPE_AGENT); }
DEV void stAf(float* p, float v){ __hip_atomic_store(p, v, __ATOMIC_RELAXED, __HIP_MEMORY_SCOPE_AGENT); }
DEV u32  ldA32(const u32* p){ return __hip_atomic_load(p, __ATOMIC_RELAXED, __HIP_MEMORY_SCOPE_AGENT); }

// tagged h exchange: hi32 = f32 bits, lo32 = step tag
DEV u64 packHV(float h, u32 tag){ return (((u64)__float_as_uint(h)) << 32) | (u64)tag; }
DEV float unpackH(u64 v){ return __uint_as_float((u32)(v >> 32)); }

// tagged argmax key: [mapped f32 (32b)][0x1FFFF - row (17b)][tag (15b)]
DEV u64 packKeyT(float v, u32 row, u32 tagv){
  u32 u = __float_as_uint(v);
  u = (u & 0x80000000u) ? ~u : (u | 0x80000000u);
  return (((u64)u) << 32) | ((u64)(0x1FFFFu - row) << 15) | (u64)tagv;
}

// fp16 row fragment (8 halves in a uint4) dotted with 8 f32 inputs (f32 math)
DEV float dot8h(const uint4 A, const float4 a, const float4 b){
  const __half2* h = (const __half2*)&A;
  const float2 f0 = __half22float2(h[0]);
  const float2 f1 = __half22float2(h[1]);
  const float2 f2 = __half22float2(h[2]);
  const float2 f3 = __half22float2(h[3]);
  float s;
  s  = f0.x*a.x + f0.y*a.y + f1.x*a.z + f1.y*a.w;
  s += f2.x*b.x + f2.y*b.y + f3.x*b.z + f3.y*b.w;
  return s;
}

DEV float dotrow(const float4 A, const float4 B, const float4 Cc, const float4 D,
                 const float4 q0, const float4 q1, const float4 q2, const float4 q3){
  float s;
  s  = A.x*q0.x + A.y*q0.y + A.z*q0.z + A.w*q0.w;
  s += B.x*q1.x + B.y*q1.y + B.z*q1.z + B.w*q1.w;
  s += Cc.x*q2.x + Cc.y*q2.y + Cc.z*q2.z + Cc.w*q2.w;
  s += D.x*q3.x + D.y*q3.y + D.z*q3.z + D.w*q3.w;
  return s;
}

// ---------------- LDS ----------------
struct SM {
  float w1s[24576];    // 96 KB decoder layer-1 weights (thread-SoA)
  float inpP[1600];
  float linp[1024];    // h1(t) raw; doubles as h1 cache for L1(t+1)
  float h0c[1024];     // h0(t) raw cache (filled during L1's poll) for L0(t+1)
  float srow[200];
  float erow[200];
  float red[16];       // [0..3] pabs partials, [8..15] lb partials (8 waves)
  float dots[16];
  float cst0[4];
  float cst1[4];
  u64   wkey[8];
};

template<int CPT> DEV int pidx(int c){ int b = c / CPT; return b * (CPT + 4) + (c - b * CPT); }

template<int CPT, int DIN>
DEV void loadw(float* wreg, const float* Wih, const float* Whh, int jb4){
  const int tid = threadIdx.x, r = tid >> 4, p = tid & 15;
  const int R = 512 * (r >> 2) + jb4 + (r & 3);
  const float* s1 = Wih + (size_t)R * DIN;
  const float* s2 = Whh + (size_t)R * 512;
  #pragma unroll
  for (int k = 0; k < CPT; k += 4){
    const int col = p * CPT + k;
    const float4 v = *(const float4*)((col < DIN) ? (s1 + col) : (s2 + col - DIN));
    wreg[k] = v.x; wreg[k+1] = v.y; wreg[k+2] = v.z; wreg[k+3] = v.w;
  }
}

template<int CPT>
DEV void dot16(const float* wreg, const float* inpP, float* dots){
  const int tid = threadIdx.x, p = tid & 15;
  const float* xi = inpP + p * (CPT + 4);
  float acc = 0.f;
  #pragma unroll
  for (int k = 0; k < CPT; k += 4){
    const float4 xv = *(const float4*)(xi + k);
    acc = fmaf(wreg[k],   xv.x, acc);
    acc = fmaf(wreg[k+1], xv.y, acc);
    acc = fmaf(wreg[k+2], xv.z, acc);
    acc = fmaf(wreg[k+3], xv.w, acc);
  }
  #pragma unroll
  for (int s = 1; s < 16; s <<= 1) acc += __shfl_xor(acc, s, 64);
  if (p == 0) dots[tid >> 4] = acc;
}

DEV void dot16_w1(const float* w1s, const float* inpP, float* dots){
  const int tid = threadIdx.x, p = tid & 15;
  const float* xi = inpP + p * 100;
  float acc = 0.f;
  #pragma unroll
  for (int k = 0; k < 96; k += 4){
    const float4 w4 = *(const float4*)(w1s + (k >> 2) * 1024 + tid * 4);
    const float4 xv = *(const float4*)(xi + k);
    acc = fmaf(w4.x, xv.x, acc);
    acc = fmaf(w4.y, xv.y, acc);
    acc = fmaf(w4.z, xv.z, acc);
    acc = fmaf(w4.w, xv.w, acc);
  }
  #pragma unroll
  for (int s = 1; s < 16; s <<= 1) acc += __shfl_xor(acc, s, 64);
  if (p == 0) dots[tid >> 4] = acc;
}

// ---------------- phase barrier (used twice, encoder only) ----------------
DEV void gbar_phase(u32* g, u32 ev){
  __syncthreads();
  if (threadIdx.x == 0){
    __hip_atomic_fetch_add(g, 1u, __ATOMIC_RELEASE, __HIP_MEMORY_SCOPE_AGENT);
    const u32 tgt = 256u * ev;
    while (ldA32(g) < tgt) __builtin_amdgcn_s_sleep(8);
    (void)__hip_atomic_fetch_add(g, 0u, __ATOMIC_ACQUIRE, __HIP_MEMORY_SCOPE_AGENT);
    asm volatile("" ::: "memory");
  }
  __syncthreads();
}

// ---------------- encoder layer (R11 math; waves 4-7 parked at barriers) ----------------
template<int DIN, bool WRITE_XS>
DEV void enc_layer(const float* __restrict__ xg, float* __restrict__ xs_out,
                   const float* __restrict__ Wih, const float* __restrict__ Whh,
                   const float* __restrict__ bias,
                   u64* __restrict__ ht, float* __restrict__ hfinL, float* __restrict__ cfinL,
                   const int dir, const int jb4, SM& sm)
{
  constexpr int CPT = (DIN + 512) / 16;
  constexpr int NX  = DIN / 256;
  const int tid = threadIdx.x;
  const bool act = tid < 256;
  float wreg[CPT];
  if (act)
    loadw<CPT, DIN>(wreg, Wih + (size_t)dir * 2048 * DIN, Whh + (size_t)dir * 2048 * 512, jb4);
  float b_i = 0.f, b_f = 0.f, b_g = 0.f, b_o = 0.f;
  if (tid < 4){
    const int j = jb4 + tid;
    sm.cst0[tid] = 0.f;
    b_i = bias[dir*2048 +        j];
    b_f = bias[dir*2048 +  512 + j];
    b_g = bias[dir*2048 + 1024 + j];
    b_o = bias[dir*2048 + 1536 + j];
  }
  float xr[NX];
  if (act){
    const int t0 = dir ? 1023 : 0;
    #pragma unroll
    for (int i = 0; i < NX; ++i){
      const int c = tid + 256 * i;
      xr[i] = (DIN == 512) ? xg[(size_t)t0 * DIN + c] : ldAf(xg + (size_t)t0 * DIN + c);
    }
  }
  for (int step = 0; step < 1024; ++step){
    if (act){
      #pragma unroll
      for (int i = 0; i < NX; ++i) sm.inpP[pidx<CPT>(tid + 256 * i)] = xr[i];
      const u64* hp = ht + (step & 1) * 512;
      const u32 want = (u32)step;
      u64 a = ldA64(hp + tid*2), b = ldA64(hp + tid*2 + 1);
      while ((u32)a != want){ __builtin_amdgcn_s_sleep(1); a = ldA64(hp + tid*2); }
      while ((u32)b != want){ __builtin_amdgcn_s_sleep(1); b = ldA64(hp + tid*2 + 1); }
      sm.inpP[pidx<CPT>(DIN + tid*2)]     = unpackH(a);
      sm.inpP[pidx<CPT>(DIN + tid*2 + 1)] = unpackH(b);
    }
    __syncthreads();
    if (act){
      if (step < 1023){
        const int tn = dir ? (1022 - step) : (step + 1);
        #pragma unroll
        for (int i = 0; i < NX; ++i){
          const int c = tid + 256 * i;
          xr[i] = (DIN == 512) ? xg[(size_t)tn * DIN + c] : ldAf(xg + (size_t)tn * DIN + c);
        }
      }
      dot16<CPT>(wreg, sm.inpP, sm.dots);
    }
    __syncthreads();
    if (tid < 4){
      const float gi = sm.dots[tid]      + b_i;
      const float gf = sm.dots[4 + tid]  + b_f;
      const float gg = sm.dots[8 + tid]  + b_g;
      const float go = sm.dots[12 + tid] + b_o;
      const float cc = sigf(gf) * sm.cst0[tid] + sigf(gi) * tanhf(gg);
      const float hh = sigf(go) * tanhf(cc);
      sm.cst0[tid] = cc;
      const int t = dir ? (1023 - step) : step;
      const int j = jb4 + tid;
      stA64(ht + ((step + 1) & 1) * 512 + j, packHV(hh, (u32)(step + 1)));
      if (WRITE_XS) stAf(xs_out + (size_t)t * 1024 + dir * 512 + j, hh);
      if (step == 1023){ stAf(hfinL + dir*512 + j, hh); stAf(cfinL + dir*512 + j, cc); }
    }
    __syncthreads();
  }
}

// ---------------- init ----------------
__global__ void bilstm_init(u32* ws){
  for (u32 i = threadIdx.x; i < 32768u; i += 256u) ws[i] = 0u;
}

// ---------------- lin_W f32 -> fp16 + per-row max|w| (R11 verbatim) ----------------
__global__ void cvt_lin(const float* __restrict__ w, uint4* __restrict__ o,
                        float* __restrict__ maxw, const int C){
  const int wv = threadIdx.x >> 6, lane = threadIdx.x & 63;
  const int stride = gridDim.x * 4;
  for (int r = blockIdx.x * 4 + wv; r < C; r += stride){
    const float4* src = (const float4*)(w + (size_t)r * 1024) + lane * 4;
    const float4 v0 = src[0], v1 = src[1], v2 = src[2], v3 = src[3];
    uint4 p0, p1;
    __half2 h;
    h = __floats2half2_rn(v0.x, v0.y); p0.x = *(const u32*)&h;
    h = __floats2half2_rn(v0.z, v0.w); p0.y = *(const u32*)&h;
    h = __floats2half2_rn(v1.x, v1.y); p0.z = *(const u32*)&h;
    h = __floats2half2_rn(v1.z, v1.w); p0.w = *(const u32*)&h;
    h = __floats2half2_rn(v2.x, v2.y); p1.x = *(const u32*)&h;
    h = __floats2half2_rn(v2.z, v2.w); p1.y = *(const u32*)&h;
    h = __floats2half2_rn(v3.x, v3.y); p1.z = *(const u32*)&h;
    h = __floats2half2_rn(v3.z, v3.w); p1.w = *(const u32*)&h;
    uint4* dst = o + (size_t)r * 128 + lane * 2;
    dst[0] = p0; dst[1] = p1;
    float m = fmaxf(fmaxf(fmaxf(fabsf(v0.x), fabsf(v0.y)), fmaxf(fabsf(v0.z), fabsf(v0.w))),
                    fmaxf(fmaxf(fabsf(v1.x), fabsf(v1.y)), fmaxf(fabsf(v1.z), fabsf(v1.w))));
    m = fmaxf(m, fmaxf(fmaxf(fabsf(v2.x), fabsf(v2.y)), fmaxf(fabsf(v2.z), fabsf(v2.w))));
    m = fmaxf(m, fmaxf(fmaxf(fabsf(v3.x), fabsf(v3.y)), fmaxf(fabsf(v3.z), fabsf(v3.w))));
    #pragma unroll
    for (int s = 1; s < 64; s <<= 1) m = fmaxf(m, __shfl_xor(m, s, 64));
    if (lane == 0) maxw[r] = m;
  }
}

// ---------------- persistent kernel (512 threads: 8-wave scan, 4-wave control) ----------------
template<int LINFP16>
__global__ __launch_bounds__(512, 1)
void bilstm_persist(const float* __restrict__ x,
                    const float* __restrict__ eW0, const float* __restrict__ eU0, const float* __restrict__ eb0,
                    const float* __restrict__ eW1, const float* __restrict__ eU1, const float* __restrict__ eb1,
                    const float* __restrict__ dW0, const float* __restrict__ dU0, const float* __restrict__ db0,
                    const float* __restrict__ dW1, const float* __restrict__ dU1, const float* __restrict__ db1,
                    const float* __restrict__ linW, const float* __restrict__ linb,
                    const float* __restrict__ emb, const float* __restrict__ bos,
                    float* __restrict__ out, float* __restrict__ ws, const int L, const int C)
{
  __shared__ SM sm;
  const int w = blockIdx.x;
  const int tid = threadIdx.x;
  const bool act = tid < 256;
  const int dir = (w >> 2) & 1;                    // dir confined to 4 XCDs
  const int jb4 = ((w >> 3) * 4 + (w & 3)) * 4;

  u64*  htagE = (u64*)ws;                          // [0,32768)
  u64*  h0t   = htagE + 4096;                      // [32768,49152)
  u64*  h1t   = h0t + 2048;                        // [49152,65536)
  float* hfin = (float*)(h1t + 2048);              // [65536,73728)
  float* cfin = hfin + 2048;                       // [73728,81920)
  u32*  gbar  = (u32*)(cfin + 2048);               // [81920,81924)
  u64*  gkey  = (u64*)((char*)ws + 98304);         // [98304,131072): 256 x 128B slots
  const u16*  linH = (const u16*)((const char*)ws + 131072);
  const float* maxw = (const float*)((const char*)ws + 131072 + (size_t)C * 2048);
  float* xs1  = out;                               // scratch; decoder rewrites all of out

  // ================= encoder =================
  enc_layer<512,  true >(x,   xs1,     eW0, eU0, eb0, htagE + (0*2 + dir)*1024, hfin,        cfin,        dir, jb4, sm);
  gbar_phase(gbar, 1);
  enc_layer<1024, false>(xs1, nullptr, eW1, eU1, eb1, htagE + (1*2 + dir)*1024, hfin + 1024, cfin + 1024, dir, jb4, sm);
  gbar_phase(gbar, 2);

  // ================= decoder =================
  float w0reg[64];
  if (act)
    loadw<64, 512>(w0reg, dW0 + (size_t)dir*2048*512, dU0 + (size_t)dir*2048*512, jb4);
  if (act){ // stage layer-1 weights into LDS SoA
    const int r = tid >> 4, p = tid & 15;
    const int R = 512 * (r >> 2) + jb4 + (r & 3);
    const float* s1 = dW1 + (size_t)dir*2048*1024 + (size_t)R * 1024;
    const float* s2 = dU1 + (size_t)dir*2048*512  + (size_t)R * 512;
    #pragma unroll
    for (int k = 0; k < 96; k += 4){
      const int col = p * 96 + k;
      const float4 v = *(const float4*)((col < 1024) ? (s1 + col) : (s2 + col - 1024));
      *(float4*)(sm.w1s + (k >> 2) * 1024 + tid * 4) = v;
    }
  }

  float b0i=0,b0f=0,b0g=0,b0o=0, b1i=0,b1f=0,b1g=0,b1o=0;
  if (tid < 4){
    const int j = jb4 + tid;
    sm.cst0[tid] = ldAf(&cfin[dir*512 + j]);
    sm.cst1[tid] = ldAf(&cfin[1024 + dir*512 + j]);
    b0i = db0[dir*2048 + j];        b0f = db0[dir*2048 + 512 + j];
    b0g = db0[dir*2048 + 1024 + j]; b0o = db0[dir*2048 + 1536 + j];
    b1i = db1[dir*2048 + j];        b1f = db1[dir*2048 + 512 + j];
    b1g = db1[dir*2048 + 1024 + j]; b1o = db1[dir*2048 + 1536 + j];
  }
  const int rbase = w * 196 + (w < 81 ? w : 81);
  const int rn    = 196 + (w < 81 ? 1 : 0);
  int tok = 0;

  for (int t = 0; t < L; ++t){
    const u32 tag = (u32)(t + 1);
    // ---- layer 0 (h-half from h0c LDS cache for t>0) ----
    {
      if (act){
        const float* src = (t == 0) ? bos : (emb + (size_t)tok * 512);
        sm.inpP[pidx<64>(tid)]       = src[tid];
        sm.inpP[pidx<64>(tid + 256)] = src[tid + 256];
        if (t == 0){
          sm.inpP[pidx<64>(512 + tid*2)]     = ldAf(&hfin[dir*512 + tid*2]);
          sm.inpP[pidx<64>(512 + tid*2 + 1)] = ldAf(&hfin[dir*512 + tid*2 + 1]);
        } else {
          sm.inpP[pidx<64>(512 + tid*2)]     = sm.h0c[dir*512 + tid*2];
          sm.inpP[pidx<64>(512 + tid*2 + 1)] = sm.h0c[dir*512 + tid*2 + 1];
        }
      }
      __syncthreads();
      if (act) dot16<64>(w0reg, sm.inpP, sm.dots);
      __syncthreads();
      if (tid < 4){
        const float gi = sm.dots[tid] + b0i, gf = sm.dots[4+tid] + b0f;
        const float gg = sm.dots[8+tid] + b0g, go = sm.dots[12+tid] + b0o;
        const float cc = sigf(gf) * sm.cst0[tid] + sigf(gi) * tanhf(gg);
        const float hh = sigf(go) * tanhf(cc);
        sm.cst0[tid] = cc;
        stA64(h0t + (dir*2 + (t & 1))*512 + jb4 + tid, packHV(hh, tag));
      }
      __syncthreads();
    }

    // ---- layer 1 (polls h0(t); h1(t-1) from linp cache) ----
    {
      if (act){
        #pragma unroll
        for (int i = 0; i < 4; ++i){
          const int c = tid + 256 * i;
          const int d = c >> 9, idx = c & 511;
          const u64* hp = h0t + (d*2 + (t & 1)) * 512 + idx;
          u64 v = ldA64(hp);
          while ((u32)v != tag){ __builtin_amdgcn_s_sleep(1); v = ldA64(hp); }
          const float hv = unpackH(v);
          sm.inpP[pidx<96>(c)] = hv;
          sm.h0c[c] = hv;                            // cache for L0(t+1)
        }
        if (t == 0){
          sm.inpP[pidx<96>(1024 + tid*2)]     = ldAf(&hfin[1024 + dir*512 + tid*2]);
          sm.inpP[pidx<96>(1024 + tid*2 + 1)] = ldAf(&hfin[1024 + dir*512 + tid*2 + 1]);
        } else {
          sm.inpP[pidx<96>(1024 + tid*2)]     = sm.linp[dir*512 + tid*2];
          sm.inpP[pidx<96>(1024 + tid*2 + 1)] = sm.linp[dir*512 + tid*2 + 1];
        }
      }
      __syncthreads();
      if (act) dot16_w1(sm.w1s, sm.inpP, sm.dots);
      __syncthreads();
      if (tid < 4){
        const float gi = sm.dots[tid] + b1i, gf = sm.dots[4+tid] + b1f;
        const float gg = sm.dots[8+tid] + b1g, go = sm.dots[12+tid] + b1o;
        const float cc = sigf(gf) * sm.cst1[tid] + sigf(gi) * tanhf(gg);
        const float hh = sigf(go) * tanhf(cc);
        sm.cst1[tid] = cc;
        stA64(h1t + (dir*2 + (t & 1))*512 + jb4 + tid, packHV(hh, tag));
      }
    }

    // ---- linear + local argmax (scan over ALL 8 waves) ----
    {
      const int wv = tid >> 6, lane = tid & 63;
      if (act){
        float pabs = 0.f;
        #pragma unroll
        for (int i = 0; i < 4; ++i){
          const int c = tid + 256 * i;
          const int d = c >> 9, idx = c & 511;
          const u64* hp = h1t + (d*2 + (t & 1)) * 512 + idx;
          u64 v = ldA64(hp);
          while ((u32)v != tag){ __builtin_amdgcn_s_sleep(1); v = ldA64(hp); }
          const float hv = unpackH(v);
          sm.linp[c] = hv;                           // doubles as h1 cache for L1(t+1)
          pabs += fabsf(hv);
        }
        if constexpr (LINFP16){
          #pragma unroll
          for (int s = 1; s < 64; s <<= 1) pabs += __shfl_xor(pabs, s, 64);
          if (lane == 0) sm.red[wv] = pabs;
        }
      }
      __syncthreads();

      const float4* ip4 = (const float4*)(sm.linp + lane * 16);
      const float4 q0 = ip4[0], q1 = ip4[1], q2 = ip4[2], q3 = ip4[3];
      u64 kmax = 0;
      const int rmaxr = rbase + rn - 1;

      if constexpr (LINFP16){
        const float sumabs = sm.red[0] + sm.red[1] + sm.red[2] + sm.red[3];
        const float cErr = sumabs * 7.5e-4f;
        float lb = -1e30f;
        // 8 waves x 4 rows per iteration (row i handled by wave i&7; chains == R11)
        for (int i0 = wv; i0 < rn; i0 += 32){
          const int ia = i0;
          const int ib = (i0 + 8  > rn - 1) ? rn - 1 : i0 + 8;
          const int ic = (i0 + 16 > rn - 1) ? rn - 1 : i0 + 16;
          const int id = (i0 + 24 > rn - 1) ? rn - 1 : i0 + 24;
          const int ra = rbase + ia, rb = rbase + ib, rc = rbase + ic, rd = rbase + id;
          const uint4* pa = (const uint4*)(linH + (size_t)ra * 1024) + lane * 2;
          const uint4* pb = (const uint4*)(linH + (size_t)rb * 1024) + lane * 2;
          const uint4* pc = (const uint4*)(linH + (size_t)rc * 1024) + lane * 2;
          const uint4* pd = (const uint4*)(linH + (size_t)rd * 1024) + lane * 2;
          const uint4 A0 = pa[0], A1 = pa[1];
          const uint4 B0 = pb[0], B1 = pb[1];
          const uint4 C0 = pc[0], C1 = pc[1];
          const uint4 D0 = pd[0], D1 = pd[1];
          float sa = dot8h(A0, q0, q1) + dot8h(A1, q2, q3);
          float sb = dot8h(B0, q0, q1) + dot8h(B1, q2, q3);
          float sc = dot8h(C0, q0, q1) + dot8h(C1, q2, q3);
          float sd = dot8h(D0, q0, q1) + dot8h(D1, q2, q3);
          #pragma unroll
          for (int sh = 1; sh < 64; sh <<= 1){
            sa += __shfl_xor(sa, sh, 64);
            sb += __shfl_xor(sb, sh, 64);
            sc += __shfl_xor(sc, sh, 64);
            sd += __shfl_xor(sd, sh, 64);
          }
          if (lane == 0){
            sa += linb[ra]; sb += linb[rb]; sc += linb[rc]; sd += linb[rd];
            out[(size_t)t * C + ra] = sa;
            out[(size_t)t * C + rb] = sb;
            out[(size_t)t * C + rc] = sc;
            out[(size_t)t * C + rd] = sd;
            const float ea = maxw[ra] * cErr + 1e-4f;
            const float eb = maxw[rb] * cErr + 1e-4f;
            const float ec = maxw[rc] * cErr + 1e-4f;
            const float ed = maxw[rd] * cErr + 1e-4f;
            sm.srow[ia] = sa; sm.erow[ia] = ea;
            sm.srow[ib] = sb; sm.erow[ib] = eb;
            sm.srow[ic] = sc; sm.erow[ic] = ec;
            sm.srow[id] = sd; sm.erow[id] = ed;
            lb = fmaxf(lb, sa - ea); lb = fmaxf(lb, sb - eb);
            lb = fmaxf(lb, sc - ec); lb = fmaxf(lb, sd - ed);
          }
        }
        if (lane == 0) sm.red[8 + wv] = lb;
        __syncthreads();
        float Lb = sm.red[8];
        #pragma unroll
        for (int i = 9; i < 16; ++i) Lb = fmaxf(Lb, sm.red[i]);
        // exact f32 recheck of candidates (provably includes the WG's true argmax)
        for (int i = wv; i < rn; i += 8){
          if (sm.srow[i] + sm.erow[i] >= Lb){
            const int row = rbase + i;
            const float4* wp = (const float4*)(linW + (size_t)row * 1024) + lane * 4;
            float s = dotrow(wp[0], wp[1], wp[2], wp[3], q0, q1, q2, q3);
            #pragma unroll
            for (int sh2 = 1; sh2 < 64; sh2 <<= 1) s += __shfl_xor(s, sh2, 64);
            if (lane == 0){
              s += linb[row];
              const u64 k = packKeyT(s, (u32)row, tag);
              if (k > kmax) kmax = k;
            }
          }
        }
      } else {
        for (int i0 = wv; i0 < rn; i0 += 32){
          const int ra = rbase + i0;
          const int rb = (rbase + i0 + 8  > rmaxr) ? rmaxr : rbase + i0 + 8;
          const int rc = (rbase + i0 + 16 > rmaxr) ? rmaxr : rbase + i0 + 16;
          const int rd = (rbase + i0 + 24 > rmaxr) ? rmaxr : rbase + i0 + 24;
          const float ba = linb[ra], bb = linb[rb], bc = linb[rc], bd = linb[rd];
          const float4* pa = (const float4*)(linW + (size_t)ra * 1024) + lane * 4;
          const float4* pb = (const float4*)(linW + (size_t)rb * 1024) + lane * 4;
          const float4* pc = (const float4*)(linW + (size_t)rc * 1024) + lane * 4;
          const float4* pd = (const float4*)(linW + (size_t)rd * 1024) + lane * 4;
          const float4 a0 = pa[0], a1 = pa[1], a2 = pa[2], a3 = pa[3];
          const float4 e0 = pb[0], e1 = pb[1], e2 = pb[2], e3 = pb[3];
          const float4 c0 = pc[0], c1 = pc[1], c2 = pc[2], c3 = pc[3];
          const float4 d0 = pd[0], d1 = pd[1], d2 = pd[2], d3 = pd[3];
          float sa = dotrow(a0,a1,a2,a3, q0,q1,q2,q3);
          float sb = dotrow(e0,e1,e2,e3, q0,q1,q2,q3);
          float sc = dotrow(c0,c1,c2,c3, q0,q1,q2,q3);
          float sd = dotrow(d0,d1,d2,d3, q0,q1,q2,q3);
          #pragma unroll
          for (int sh = 1; sh < 64; sh <<= 1){
            sa += __shfl_xor(sa, sh, 64);
            sb += __shfl_xor(sb, sh, 64);
            sc += __shfl_xor(sc, sh, 64);
            sd += __shfl_xor(sd, sh, 64);
          }
          if (lane == 0){
            sa += ba; sb += bb; sc += bc; sd += bd;
            out[(size_t)t * C + ra] = sa;
            out[(size_t)t * C + rb] = sb;
            out[(size_t)t * C + rc] = sc;
            out[(size_t)t * C + rd] = sd;
            u64 k;
            k = packKeyT(sa, (u32)ra, tag); if (k > kmax) kmax = k;
            k = packKeyT(sb, (u32)rb, tag); if (k > kmax) kmax = k;
            k = packKeyT(sc, (u32)rc, tag); if (k > kmax) kmax = k;
            k = packKeyT(sd, (u32)rd, tag); if (k > kmax) kmax = k;
          }
        }
      }
      if (lane == 0) sm.wkey[wv] = kmax;
    }

    // ---- distributed argmax exchange ----
    __syncthreads();
    if (tid == 0){
      u64 k4 = sm.wkey[0];
      #pragma unroll
      for (int i = 1; i < 8; ++i) if (sm.wkey[i] > k4) k4 = sm.wkey[i];
      stA64(gkey + (size_t)w * 16, k4);              // own 128-B slot: no contention
    }
    __syncthreads();
    if (act){
      const u64* p = gkey + (size_t)tid * 16;        // thread i polls WG i's slot
      u64 kv = ldA64(p);
      while ((u32)(kv & 0x7FFFu) != tag){ __builtin_amdgcn_s_sleep(1); kv = ldA64(p); }
      #pragma unroll
      for (int s = 1; s < 64; s <<= 1){
        const u64 o = (u64)__shfl_xor((unsigned long long)kv, s, 64);
        if (o > kv) kv = o;
      }
      if ((tid & 63) == 0) sm.wkey[tid >> 6] = kv;
    }
    __syncthreads();
    {
      u64 gk = sm.wkey[0];
      if (sm.wkey[1] > gk) gk = sm.wkey[1];
      if (sm.wkey[2] > gk) gk = sm.wkey[2];
      if (sm.wkey[3] > gk) gk = sm.wkey[3];
      tok = (int)(0x1FFFFu - ((u32)(gk >> 15) & 0x1FFFFu));
      if (w == 0 && tid == 0) out[(size_t)L * C + t] = (float)tok;
    }
  }
}

// ---------------- launch ----------------
extern "C" void kernel_launch(void* const* d_in, const int* in_sizes, int n_in,
                              void* d_out, int out_size, void* d_ws, size_t ws_size,
                              hipStream_t stream)
{
  const float* x    = (const float*)d_in[0];
  const float* eW0  = (const float*)d_in[1];
  const float* eU0  = (const float*)d_in[2];
  const float* eb0  = (const float*)d_in[3];
  const float* eW1  = (const float*)d_in[4];
  const float* eU1  = (const float*)d_in[5];
  const float* eb1  = (const float*)d_in[6];
  const float* dW0  = (const float*)d_in[7];
  const float* dU0  = (const float*)d_in[8];
  const float* db0  = (const float*)d_in[9];
  const float* dW1  = (const float*)d_in[10];
  const float* dU1  = (const float*)d_in[11];
  const float* db1  = (const float*)d_in[12];
  const float* linW = (const float*)d_in[13];
  const float* linb = (const float*)d_in[14];
  const float* emb  = (const float*)d_in[15];
  const float* bos  = (const float*)d_in[16];

  const int C = in_sizes[14];            // 50257
  const int L = out_size / (C + 1);      // 150
  const int nlin = in_sizes[13];         // C*1024

  const size_t need = 131072 + (size_t)nlin * 2 + (size_t)C * 4;
  const bool fp16lin = (ws_size >= need);

  hipLaunchKernelGGL(bilstm_init, dim3(1), dim3(256), 0, stream, (u32*)d_ws);
  if (fp16lin){
    hipLaunchKernelGGL(cvt_lin, dim3(2048), dim3(256), 0, stream,
                       linW, (uint4*)((char*)d_ws + 131072),
                       (float*)((char*)d_ws + 131072 + (size_t)C * 2048), C);
    hipLaunchKernelGGL((bilstm_persist<1>), dim3(256), dim3(512), 0, stream,
                       x, eW0, eU0, eb0, eW1, eU1, eb1,
                       dW0, dU0, db0, dW1, dU1, db1,
                       linW, linb, emb, bos,
                       (float*)d_out, (float*)d_ws, L, C);
  } else {
    hipLaunchKernelGGL((bilstm_persist<0>), dim3(256), dim3(512), 0, stream,
                       x, eW0, eU0, eb0, eW1, eU1, eb1,
                       dW0, dU0, db0, dW1, dU1, db1,
                       linW, linb, emb, bos,
                       (float*)d_out, (float*)d_ws, L, C);
  }
}